// Round 3
// baseline (12461.830 us; speedup 1.0000x reference)
//
#include <hip/hip_runtime.h>
#include <hip/hip_cooperative_groups.h>
#include <math.h>

namespace cg = cooperative_groups;

#define BB 8
#define TT 12
#define NN 716
#define EE 10
#define HH 64
#define DIN 65
#define OG 128
#define OU 64
#define XSP 68     // padded xs / parts row stride
#define JS 8       // j-split for xg2 gemm
#define JR 90      // ceil(716/8)
#define NP 768     // padded n for parts
#define GRID_MAX 768

__device__ __forceinline__ float sigmf(float x){ return 1.0f/(1.0f+__expf(-x)); }

struct Params {
  const float *ne, *wp_g, *bp_g, *wp_u, *bp_u;
  const float *f1W_g, *f1b_g, *f2W_g, *f2b_g, *f3W_g, *f3b_g;
  const float *f1W_u, *f1b_u, *f2W_u, *f2b_u, *f3W_u, *f3b_u;
  const float *predW, *predB, *skipW, *skipB;
  float *emb, *cur, *wg, *bg, *wu, *bu, *h, *xsg, *xsu, *nv, *d, *parts, *rbuf, *out;
};

// ---------------- emb precompute + cur0 (separate tiny kernel) ----------------
__global__ void k_emb(const float* __restrict__ src, const float* __restrict__ ne,
                      const float* __restrict__ te, const float* __restrict__ de,
                      float* __restrict__ emb, float* __restrict__ cur){
  int idx = blockIdx.x*256 + threadIdx.x;
  if (idx >= BB*TT*NN) return;
  int n = idx % NN; int t = (idx/NN) % TT; int b = idx/(NN*TT);
  const float* s = src + (size_t)idx*3;
  float x = s[0];
  int ti = (int)(s[1]*288.0f);
  int di = (int)(s[2]);
  size_t eo = ((size_t)b*TT + t)*NN*EE + (size_t)n*EE;
  #pragma unroll
  for (int e=0;e<EE;e++)
    emb[eo+e] = ne[n*EE+e]*te[ti*EE+e]*de[di*EE+e];
  cur[((size_t)t*BB + b)*NN + n] = x;   // cur[0][t][b][n]
}

// ================= device phase functions =================

// w = static@wp for one (k,i) slab x n-half. task = ki*2+half.
__device__ void ph_prep_w(const float* ne, const float* wp, float* w, int O,
                          int task, int tid, float* sm){
  int ki = task >> 1, half = task & 1;
  int k = ki / DIN, i = ki - k*DIN;
  for (int idx=tid; idx<EE*O; idx+=256){
    int e = idx / O, o = idx - e*O;
    sm[idx] = wp[(((size_t)e*2+k)*DIN+i)*O + o];
  }
  __syncthreads();
  int NG = 256/O;
  int o = tid & (O-1), ng = tid / O;
  int nend = half*358+358; if (nend>NN) nend=NN;
  for (int n = half*358+ng; n < nend; n += NG){
    float acc = 0.f;
    #pragma unroll
    for (int e=0;e<EE;e++) acc += ne[n*EE+e]*sm[e*O+o];
    w[(((size_t)n*2+k)*DIN+i)*O + o] = acc;
  }
  __syncthreads();  // sm reuse across tasks
}

// biases + h=0 + xs/nv init for layer c; strided over all grid threads
__device__ void ph_misc(const Params& p, int c, int mt, int MT){
  for (int i=mt; i<BB*NN*HH; i+=MT) p.h[i] = 0.f;
  const float* bpg = p.bp_g + (size_t)c*EE*OG;
  for (int i=mt; i<NN*OG; i+=MT){
    int o=i&(OG-1), n=i>>7; float a=0.f;
    #pragma unroll
    for (int e=0;e<EE;e++) a += p.ne[n*EE+e]*bpg[e*OG+o];
    p.bg[i]=a;
  }
  const float* bpu = p.bp_u + (size_t)c*EE*OU;
  for (int i=mt; i<NN*OU; i+=MT){
    int o=i&(OU-1), n=i>>6; float a=0.f;
    #pragma unroll
    for (int e=0;e<EE;e++) a += p.ne[n*EE+e]*bpu[e*OU+o];
    p.bu[i]=a;
  }
  const float* f1W=p.f1W_g + c*16*DIN; const float* f1b=p.f1b_g + c*16;
  const float* f2W=p.f2W_g + c*32;     const float* f2b=p.f2b_g + c*2;
  const float* f3W=p.f3W_g + c*EE*2;   const float* f3b=p.f3b_g + c*EE;
  for (int idx=mt; idx<BB*NN; idx+=MT){
    int b=idx/NN, n=idx-b*NN;
    float x = p.cur[(((size_t)c*TT+0)*BB + b)*NN + n];
    float* xr = p.xsg + (size_t)idx*XSP;
    xr[0]=x;
    #pragma unroll
    for (int i2=1;i2<=64;i2++) xr[i2]=0.f;
    float h1[16];
    #pragma unroll
    for (int k=0;k<16;k++) h1[k]=sigmf(f1b[k]+f1W[k*DIN]*x);
    float h2[2];
    #pragma unroll
    for (int k=0;k<2;k++){
      float s=f2b[k];
      #pragma unroll
      for (int q=0;q<16;q++) s+=f2W[k*16+q]*h1[q];
      h2[k]=sigmf(s);
    }
    #pragma unroll
    for (int e=0;e<EE;e++){
      float xe=f3b[e]+f3W[e*2]*h2[0]+f3W[e*2+1]*h2[1];
      p.nv[(size_t)idx*EE+e]=tanhf(p.emb[(((size_t)b*TT+0)*NN+n)*EE+e]*xe);
    }
  }
}

// d[b][j] = rsqrt(sum_n relu(nv_j . nv_n)); task = b*90 + jt (8 j's per task)
__device__ void ph_dsum(const float* nv, float* d, int task, int tid, float* sm){
  int b = task / 90, jt = task - b*90;
  int j0 = jt*8;
  int jg = tid>>5, lane = tid&31;
  int j = j0 + jg;
  float a[EE];
  if (j < NN){
    #pragma unroll
    for (int e=0;e<EE;e++) a[e] = nv[((size_t)b*NN+j)*EE+e];
  }
  float sum = 0.f;
  for (int ncc=0; ncc<NN; ncc+=64){
    int cnt = min(64, NN-ncc);
    __syncthreads();
    for (int idx=tid; idx<cnt*EE; idx+=256){
      int r = idx/EE, e = idx - r*EE;
      sm[r*11+e] = nv[((size_t)b*NN+ncc+r)*EE+e];
    }
    __syncthreads();
    if (j < NN){
      #pragma unroll
      for (int q=0;q<2;q++){
        int nn = q*32 + lane;
        if (nn < cnt){
          float s=0.f;
          #pragma unroll
          for (int e=0;e<EE;e++) s += a[e]*sm[nn*11+e];
          sum += fmaxf(s, 0.f);
        }
      }
    }
  }
  sum += __shfl_xor(sum,16,64); sum += __shfl_xor(sum,8,64);
  sum += __shfl_xor(sum,4,64);  sum += __shfl_xor(sum,2,64);
  sum += __shfl_xor(sum,1,64);
  if (lane==0 && j<NN) d[b*NN+j] = rsqrtf(sum);
  __syncthreads();
}

// xg2 gemm with G computed on the fly; task decodes (nc, js, b)
__device__ void ph_xg2(const float* nv, const float* d, const float* xs,
                       float* parts, int task, int tid, float* sm){
  float* a_nv = sm;                                   // [64][11]
  float* b_nv = sm + 704;                             // [64][11]
  float (*xss)[XSP] = (float(*)[XSP])(sm + 1408);     // [64][68]
  float (*gs)[XSP]  = (float(*)[XSP])(sm + 1408 + 64*XSP); // [64][68]
  int nc = task % 12, js = (task/12) % 8, b = task / 96;
  int n0 = nc*64;
  int j0 = js*JR, jend = min(NN, j0+JR);
  for (int idx=tid; idx<64*EE; idx+=256){
    int r = idx/EE, e = idx - r*EE;
    int n = n0 + r;
    a_nv[r*11+e] = (n<NN) ? nv[((size_t)b*NN+n)*EE+e] : 0.f;
  }
  int ig = tid & 15, ng = tid >> 4;
  int jg = tid >> 4, ng2 = tid & 15;
  int n2 = tid & 63, q = tid >> 6;
  float acc[4][4];
  #pragma unroll
  for (int r=0;r<4;r++){ acc[r][0]=0;acc[r][1]=0;acc[r][2]=0;acc[r][3]=0; }
  float a64p = 0.f;
  for (int jc=j0; jc<jend; jc+=64){
    int cnt = min(64, jend-jc);
    __syncthreads();
    for (int idx=tid; idx<64*EE; idx+=256){
      int r = idx/EE, e = idx - r*EE;
      b_nv[r*11+e] = (r<cnt) ? nv[((size_t)b*NN+jc+r)*EE+e] : 0.f;
    }
    for (int idx=tid; idx<64*64; idx+=256){
      int r = idx>>6, ii = idx&63;
      int j = jc + r;
      xss[r][ii] = (r<cnt) ? d[b*NN+j]*xs[((size_t)b*NN+j)*XSP+ii] : 0.f;
    }
    if (tid < 64){
      int j = jc + tid;
      xss[tid][64] = (tid<cnt) ? d[b*NN+j]*xs[((size_t)b*NN+j)*XSP+64] : 0.f;
    }
    __syncthreads();
    {
      float g[4][4];
      #pragma unroll
      for (int r=0;r<4;r++){ g[r][0]=0;g[r][1]=0;g[r][2]=0;g[r][3]=0; }
      #pragma unroll
      for (int e=0;e<EE;e++){
        float b0=b_nv[(jg*4+0)*11+e], b1=b_nv[(jg*4+1)*11+e],
              b2=b_nv[(jg*4+2)*11+e], b3=b_nv[(jg*4+3)*11+e];
        float a0=a_nv[(ng2*4+0)*11+e], a1=a_nv[(ng2*4+1)*11+e],
              a2=a_nv[(ng2*4+2)*11+e], a3=a_nv[(ng2*4+3)*11+e];
        g[0][0]+=b0*a0; g[0][1]+=b0*a1; g[0][2]+=b0*a2; g[0][3]+=b0*a3;
        g[1][0]+=b1*a0; g[1][1]+=b1*a1; g[1][2]+=b1*a2; g[1][3]+=b1*a3;
        g[2][0]+=b2*a0; g[2][1]+=b2*a1; g[2][2]+=b2*a2; g[2][3]+=b2*a3;
        g[3][0]+=b3*a0; g[3][1]+=b3*a1; g[3][2]+=b3*a2; g[3][3]+=b3*a3;
      }
      #pragma unroll
      for (int r=0;r<4;r++){
        float4 v = { fmaxf(g[r][0],0.f), fmaxf(g[r][1],0.f),
                     fmaxf(g[r][2],0.f), fmaxf(g[r][3],0.f) };
        *(float4*)&gs[jg*4+r][ng2*4] = v;
      }
    }
    __syncthreads();
    for (int jj=0; jj<cnt; ++jj){
      float4 g4 = *(const float4*)&gs[jj][ng*4];
      float4 x4 = *(const float4*)&xss[jj][ig*4];
      acc[0][0]+=g4.x*x4.x; acc[0][1]+=g4.x*x4.y; acc[0][2]+=g4.x*x4.z; acc[0][3]+=g4.x*x4.w;
      acc[1][0]+=g4.y*x4.x; acc[1][1]+=g4.y*x4.y; acc[1][2]+=g4.y*x4.z; acc[1][3]+=g4.y*x4.w;
      acc[2][0]+=g4.z*x4.x; acc[2][1]+=g4.z*x4.y; acc[2][2]+=g4.z*x4.z; acc[2][3]+=g4.z*x4.w;
      acc[3][0]+=g4.w*x4.x; acc[3][1]+=g4.w*x4.y; acc[3][2]+=g4.w*x4.z; acc[3][3]+=g4.w*x4.w;
    }
    {
      #pragma unroll
      for (int r=0;r<16;r++){
        int jj = q*16 + r;
        a64p += gs[jj][n2]*xss[jj][64];
      }
    }
  }
  #pragma unroll
  for (int r=0;r<4;r++){
    int n = n0 + ng*4 + r;
    float4 v = { acc[r][0], acc[r][1], acc[r][2], acc[r][3] };
    *(float4*)&parts[(((size_t)js*BB+b)*NP+n)*XSP + ig*4] = v;
  }
  __syncthreads();
  float* red = b_nv;  // 256 floats
  red[q*64 + n2] = a64p;
  __syncthreads();
  if (tid < 64){
    float s = red[tid] + red[64+tid] + red[128+tid] + red[192+tid];
    parts[(((size_t)js*BB+b)*NP + n0+tid)*XSP + 64] = s;
  }
  __syncthreads();
}

// gate transform for node n
__device__ void ph_tr_gate(const Params& p, int c, int t, int n, int tid, float* sm){
  float* xg2s = sm;          // [8] stride 66
  float* xss  = sm + 528;    // [8] stride 65
  float* cs   = sm + 1048;   // [8] stride 65
  float* h1s  = sm + 1568;   // [8][16]
  float* h2s  = sm + 1696;   // [8][2]
  for (int idx=tid; idx<BB*65; idx+=256){
    int b=idx/65, i=idx-b*65;
    float s=0.f;
    #pragma unroll
    for (int j2=0;j2<JS;j2++) s += p.parts[(((size_t)j2*BB+b)*NP+n)*XSP+i];
    xg2s[b*66+i] = p.d[b*NN+n]*s;
  }
  for (int idx=tid; idx<BB*DIN; idx+=256){
    int b=idx/DIN, i=idx-b*DIN;
    xss[b*65+i] = p.xsg[((size_t)b*NN+n)*XSP+i];
  }
  __syncthreads();
  {
    int o = tid & 127, half = tid >> 7;
    const float* w0p = p.wg + ((size_t)n*2+0)*DIN*OG + o;
    const float* w1p = p.wg + ((size_t)n*2+1)*DIN*OG + o;
    float bgv = p.bg[n*OG+o];
    float acc[4]; acc[0]=bgv; acc[1]=bgv; acc[2]=bgv; acc[3]=bgv;
    for (int i=0;i<65;i++){
      float w0 = w0p[i*OG], w1 = w1p[i*OG];
      #pragma unroll
      for (int bb=0;bb<4;bb++){
        int b = 2*bb+half;
        acc[bb] += xss[b*65+i]*w0 + xg2s[b*66+i]*w1;
      }
    }
    #pragma unroll
    for (int bb=0;bb<4;bb++){
      int b = 2*bb+half;
      float v = sigmf(acc[bb]);
      if (o < 64){
        float cv = v * p.h[((size_t)b*NN+n)*HH + o];
        p.xsu[((size_t)b*NN+n)*XSP + 1 + o] = cv;
        cs[b*65+1+o] = cv;
      } else {
        p.rbuf[((size_t)b*NN+n)*HH + (o-64)] = v;
      }
    }
    if (o == 64){
      #pragma unroll
      for (int bb=0;bb<4;bb++){
        int b = 2*bb+half;
        float x = p.cur[(((size_t)c*TT+t)*BB+b)*NN+n];
        cs[b*65] = x;
        p.xsu[((size_t)b*NN+n)*XSP] = x;
      }
    }
  }
  __syncthreads();
  const float* f1W=p.f1W_u + c*16*DIN; const float* f1b=p.f1b_u + c*16;
  const float* f2W=p.f2W_u + c*32;     const float* f2b=p.f2b_u + c*2;
  const float* f3W=p.f3W_u + c*EE*2;   const float* f3b=p.f3b_u + c*EE;
  if (tid < BB*16){
    int b=tid>>4, k=tid&15;
    const float* wr = f1W + k*DIN;
    float s = f1b[k];
    #pragma unroll
    for (int i=0;i<DIN;i++) s += cs[b*65+i]*wr[i];
    h1s[b*16+k] = sigmf(s);
  }
  __syncthreads();
  if (tid < BB*2){
    int b=tid>>1, k=tid&1;
    float s = f2b[k];
    #pragma unroll
    for (int q2=0;q2<16;q2++) s += h1s[b*16+q2]*f2W[k*16+q2];
    h2s[b*2+k] = sigmf(s);
  }
  __syncthreads();
  if (tid < BB*EE){
    int b=tid/EE, e=tid-b*EE;
    float xe = f3b[e] + f3W[e*2]*h2s[b*2] + f3W[e*2+1]*h2s[b*2+1];
    p.nv[((size_t)b*NN+n)*EE+e] = tanhf(p.emb[(((size_t)b*TT+t)*NN+n)*EE+e]*xe);
  }
  __syncthreads();
}

// update transform for node n
__device__ void ph_tr_upd(const Params& p, int c, int t, int n, int tid, float* sm){
  float* xg2s = sm;          // stride 66
  float* xss  = sm + 528;    // stride 65
  float* hs   = sm + 1048;   // [8][64]
  float* h1s  = sm + 1568;
  float* h2s  = sm + 1696;
  float* xns  = sm + 1712;   // [8]
  for (int idx=tid; idx<BB*65; idx+=256){
    int b=idx/65, i=idx-b*65;
    float s=0.f;
    #pragma unroll
    for (int j2=0;j2<JS;j2++) s += p.parts[(((size_t)j2*BB+b)*NP+n)*XSP+i];
    xg2s[b*66+i] = p.d[b*NN+n]*s;
  }
  for (int idx=tid; idx<BB*DIN; idx+=256){
    int b=idx/DIN, i=idx-b*DIN;
    xss[b*65+i] = p.xsu[((size_t)b*NN+n)*XSP+i];
  }
  __syncthreads();
  {
    int o = tid & 63, grp = tid >> 6;
    const float* w0p = p.wu + ((size_t)n*2+0)*DIN*OU + o;
    const float* w1p = p.wu + ((size_t)n*2+1)*DIN*OU + o;
    float acc[2];
    acc[0] = p.bu[n*OU+o]; acc[1] = acc[0];
    for (int i=0;i<65;i++){
      float w0 = w0p[i*OU], w1 = w1p[i*OU];
      #pragma unroll
      for (int bb=0;bb<2;bb++){
        int b = grp + 4*bb;
        acc[bb] += xss[b*65+i]*w0 + xg2s[b*66+i]*w1;
      }
    }
    #pragma unroll
    for (int bb=0;bb<2;bb++){
      int b = grp + 4*bb;
      float hc = tanhf(acc[bb]);
      float r = p.rbuf[((size_t)b*NN+n)*HH+o];
      float hold = p.h[((size_t)b*NN+n)*HH+o];
      float hn = r*hold + (1.f-r)*hc;
      p.h[((size_t)b*NN+n)*HH+o] = hn;
      hs[b*64+o] = hn;
    }
  }
  __syncthreads();
  if (t < TT-1){
    if (tid < BB){
      float x = p.cur[(((size_t)c*TT + (t+1))*BB + tid)*NN + n];
      xns[tid] = x;
      p.xsg[((size_t)tid*NN+n)*XSP] = x;
    }
    for (int idx=tid; idx<BB*HH; idx+=256){
      int b = idx>>6, oo = idx&63;
      p.xsg[((size_t)b*NN+n)*XSP + 1 + oo] = hs[b*64+oo];
    }
    __syncthreads();
    const float* f1W=p.f1W_g + c*16*DIN; const float* f1b=p.f1b_g + c*16;
    const float* f2W=p.f2W_g + c*32;     const float* f2b=p.f2b_g + c*2;
    const float* f3W=p.f3W_g + c*EE*2;   const float* f3b=p.f3b_g + c*EE;
    if (tid < BB*16){
      int b=tid>>4, k=tid&15;
      const float* wr = f1W + k*DIN;
      float s = f1b[k] + wr[0]*xns[b];
      #pragma unroll
      for (int oo=0;oo<HH;oo++) s += hs[b*64+oo]*wr[1+oo];
      h1s[b*16+k] = sigmf(s);
    }
    __syncthreads();
    if (tid < BB*2){
      int b=tid>>1, k=tid&1;
      float s = f2b[k];
      #pragma unroll
      for (int q2=0;q2<16;q2++) s += h1s[b*16+q2]*f2W[k*16+q2];
      h2s[b*2+k] = sigmf(s);
    }
    __syncthreads();
    if (tid < BB*EE){
      int b=tid/EE, e=tid-b*EE;
      float xe = f3b[e] + f3W[e*2]*h2s[b*2] + f3W[e*2+1]*h2s[b*2+1];
      p.nv[((size_t)b*NN+n)*EE+e] =
        tanhf(p.emb[(((size_t)b*TT+(t+1))*NN+n)*EE+e]*xe);
    }
  } else {
    if (tid < BB*TT){
      int b = tid/TT, ot = tid - b*TT;
      const float* pw = p.predW + ((size_t)c*TT + ot)*HH;
      float pv = p.predB[c*TT+ot];
      #pragma unroll
      for (int q2=0;q2<HH;q2++) pv += hs[b*64+q2]*pw[q2];
      size_t oi = ((size_t)b*TT+ot)*NN + n;
      if (c == 0){
        p.out[oi] = pv;
        const float* sw = p.skipW + (size_t)ot*HH;
        float sk = p.skipB[ot];
        #pragma unroll
        for (int q2=0;q2<HH;q2++) sk += hs[b*64+q2]*sw[q2];
        p.cur[(((size_t)TT+ot)*BB + b)*NN + n] =
            p.cur[((size_t)ot*BB + b)*NN + n] - sk;
      } else {
        p.out[oi] += pv;
      }
    }
  }
  __syncthreads();
}

// ================= persistent cooperative mega-kernel =================
__global__ __launch_bounds__(256, 3) void k_main(Params p){
  cg::grid_group g = cg::this_grid();
  __shared__ __align__(16) float sm[10112];   // 40448 B
  int bid = blockIdx.x, tid = threadIdx.x;
  int gdim = gridDim.x;

  for (int c=0; c<2; c++){
    // ---- phase 0: weight prep + biases + h=0 + init xsg/nv
    for (int task=bid; task<520; task+=gdim){
      if (task < 260)
        ph_prep_w(p.ne, p.wp_g + (size_t)c*EE*2*DIN*OG, p.wg, OG, task, tid, sm);
      else
        ph_prep_w(p.ne, p.wp_u + (size_t)c*EE*2*DIN*OU, p.wu, OU, task-260, tid, sm);
    }
    ph_misc(p, c, bid*256+tid, gdim*256);
    g.sync();

    for (int t=0; t<TT; t++){
      // gate gcn
      for (int task=bid; task<720; task+=gdim) ph_dsum(p.nv, p.d, task, tid, sm);
      g.sync();
      for (int task=bid; task<768; task+=gdim) ph_xg2(p.nv, p.d, p.xsg, p.parts, task, tid, sm);
      g.sync();
      for (int n=bid; n<NN; n+=gdim) ph_tr_gate(p, c, t, n, tid, sm);
      g.sync();
      // update gcn
      for (int task=bid; task<720; task+=gdim) ph_dsum(p.nv, p.d, task, tid, sm);
      g.sync();
      for (int task=bid; task<768; task+=gdim) ph_xg2(p.nv, p.d, p.xsu, p.parts, task, tid, sm);
      g.sync();
      for (int n=bid; n<NN; n+=gdim) ph_tr_upd(p, c, t, n, tid, sm);
      g.sync();
    }
  }
}

extern "C" void kernel_launch(void* const* d_in, const int* in_sizes, int n_in,
                              void* d_out, int out_size, void* d_ws, size_t ws_size,
                              hipStream_t stream){
  const float* src  = (const float*)d_in[0];
  const float* ne   = (const float*)d_in[1];
  const float* te   = (const float*)d_in[2];
  const float* de   = (const float*)d_in[3];

  float* ws   = (float*)d_ws;
  float* emb  = ws;
  float* cur  = emb  + (size_t)BB*TT*NN*EE;
  float* wg   = cur  + (size_t)2*TT*BB*NN;
  float* bg   = wg   + (size_t)NN*2*DIN*OG;
  float* wu   = bg   + (size_t)NN*OG;
  float* bu   = wu   + (size_t)NN*2*DIN*OU;
  float* h    = bu   + (size_t)NN*OU;
  float* xsg  = h    + (size_t)BB*NN*HH;
  float* xsu  = xsg  + (size_t)BB*NN*XSP;
  float* nv   = xsu  + (size_t)BB*NN*XSP;
  float* dbuf = nv   + (size_t)BB*NN*EE;
  float* parts= dbuf + (size_t)BB*NN;
  float* rbuf = parts+ (size_t)JS*BB*NP*XSP;

  Params P;
  P.ne   = ne;
  P.wp_g = (const float*)d_in[4];  P.bp_g = (const float*)d_in[5];
  P.f1W_g= (const float*)d_in[6];  P.f1b_g= (const float*)d_in[7];
  P.f2W_g= (const float*)d_in[8];  P.f2b_g= (const float*)d_in[9];
  P.f3W_g= (const float*)d_in[10]; P.f3b_g= (const float*)d_in[11];
  P.wp_u = (const float*)d_in[12]; P.bp_u = (const float*)d_in[13];
  P.f1W_u= (const float*)d_in[14]; P.f1b_u= (const float*)d_in[15];
  P.f2W_u= (const float*)d_in[16]; P.f2b_u= (const float*)d_in[17];
  P.f3W_u= (const float*)d_in[18]; P.f3b_u= (const float*)d_in[19];
  P.predW= (const float*)d_in[20]; P.predB= (const float*)d_in[21];
  P.skipW= (const float*)d_in[22]; P.skipB= (const float*)d_in[23];
  P.emb=emb; P.cur=cur; P.wg=wg; P.bg=bg; P.wu=wu; P.bu=bu;
  P.h=h; P.xsg=xsg; P.xsu=xsu; P.nv=nv; P.d=dbuf; P.parts=parts; P.rbuf=rbuf;
  P.out=(float*)d_out;

  k_emb<<<(BB*TT*NN+255)/256, 256, 0, stream>>>(src, ne, te, de, emb, cur);

  int maxb = 0;
  hipOccupancyMaxActiveBlocksPerMultiprocessor(&maxb, (const void*)k_main, 256, 0);
  if (maxb < 1) maxb = 1;
  int grid = maxb * 256;            // 256 CUs on MI355X
  if (grid > GRID_MAX) grid = GRID_MAX;

  void* kargs[] = { (void*)&P };
  hipLaunchCooperativeKernel((const void*)k_main, dim3(grid), dim3(256),
                             kargs, 0, stream);
}

// Round 4
// 3815.089 us; speedup vs baseline: 3.2665x; 3.2665x over previous
//
#include <hip/hip_runtime.h>
#include <math.h>

#define BB 8
#define TT 12
#define NN 716
#define EE 10
#define HH 64
#define DIN 65
#define OG 128
#define OU 64
#define XSP 68     // padded xs / parts row stride
#define JS 8       // j-split for xg2 gemm
#define JR 90      // ceil(716/8)
#define JCH 32     // j-chunk inside xg2
#define NP 768     // padded n for parts

__device__ __forceinline__ float sigmf(float x){ return 1.0f/(1.0f+__expf(-x)); }

// ---------------- emb precompute + cur0 ----------------
__global__ void k_emb(const float* __restrict__ src, const float* __restrict__ ne,
                      const float* __restrict__ te, const float* __restrict__ de,
                      float* __restrict__ emb, float* __restrict__ cur){
  int idx = blockIdx.x*256 + threadIdx.x;
  if (idx >= BB*TT*NN) return;
  int n = idx % NN; int t = (idx/NN) % TT; int b = idx/(NN*TT);
  const float* s = src + (size_t)idx*3;
  float x = s[0];
  int ti = (int)(s[1]*288.0f);
  int di = (int)(s[2]);
  size_t eo = ((size_t)b*TT + t)*NN*EE + (size_t)n*EE;
  #pragma unroll
  for (int e=0;e<EE;e++)
    emb[eo+e] = ne[n*EE+e]*te[ti*EE+e]*de[di*EE+e];
  cur[((size_t)t*BB + b)*NN + n] = x;   // cur[0][t][b][n]
}

// ---------------- per-layer w = static@wp ----------------
template<int O>
__global__ __launch_bounds__(256) void k_prep_w2(
    const float* __restrict__ ne, const float* __restrict__ wp,
    float* __restrict__ w)
{
  __shared__ float wps[EE][O];
  int ki = blockIdx.x;           // 0..129
  int half = blockIdx.y;         // 0..1
  int k = ki / DIN, i = ki - k*DIN;
  int tid = threadIdx.x;
  for (int idx=tid; idx<EE*O; idx+=256){
    int e = idx / O, o = idx - e*O;
    wps[e][o] = wp[(((size_t)e*2+k)*DIN+i)*O + o];
  }
  __syncthreads();
  constexpr int NG = 256/O;
  int o = tid & (O-1), ng = tid / O;
  int nend = min(NN, half*358+358);
  for (int n = half*358 + ng; n < nend; n += NG){
    float acc = 0.f;
    #pragma unroll
    for (int e=0;e<EE;e++) acc += ne[n*EE+e]*wps[e][o];
    w[(((size_t)n*2+k)*DIN+i)*O + o] = acc;
  }
}

// ---------------- per-layer misc: biases + h=0 + xs/nv init ----------------
__global__ void k_misc(const float* __restrict__ ne,
                       const float* __restrict__ bp_g, const float* __restrict__ bp_u,
                       float* __restrict__ bg, float* __restrict__ bu,
                       float* __restrict__ h, const float* __restrict__ cur_c,
                       const float* __restrict__ f1W, const float* __restrict__ f1b,
                       const float* __restrict__ f2W, const float* __restrict__ f2b,
                       const float* __restrict__ f3W, const float* __restrict__ f3b,
                       const float* __restrict__ emb,
                       float* __restrict__ xsg, float* __restrict__ nv){
  int mt = blockIdx.x*256 + threadIdx.x;
  int MT = gridDim.x*256;
  for (int i=mt; i<BB*NN*HH; i+=MT) h[i] = 0.f;
  for (int i=mt; i<NN*OG; i+=MT){
    int o=i&(OG-1), n=i>>7; float a=0.f;
    #pragma unroll
    for (int e=0;e<EE;e++) a += ne[n*EE+e]*bp_g[e*OG+o];
    bg[i]=a;
  }
  for (int i=mt; i<NN*OU; i+=MT){
    int o=i&(OU-1), n=i>>6; float a=0.f;
    #pragma unroll
    for (int e=0;e<EE;e++) a += ne[n*EE+e]*bp_u[e*OU+o];
    bu[i]=a;
  }
  for (int idx=mt; idx<BB*NN; idx+=MT){
    int b=idx/NN, n=idx-b*NN;
    float x = cur_c[(size_t)b*NN + n];   // t = 0
    float* xr = xsg + (size_t)idx*XSP;
    xr[0]=x;
    #pragma unroll
    for (int i2=1;i2<XSP;i2++) xr[i2]=0.f;
    float h1[16];
    #pragma unroll
    for (int k=0;k<16;k++) h1[k]=sigmf(f1b[k]+f1W[k*DIN]*x);
    float h2[2];
    #pragma unroll
    for (int k=0;k<2;k++){
      float s=f2b[k];
      #pragma unroll
      for (int q=0;q<16;q++) s+=f2W[k*16+q]*h1[q];
      h2[k]=sigmf(s);
    }
    #pragma unroll
    for (int e=0;e<EE;e++){
      float xe=f3b[e]+f3W[e*2]*h2[0]+f3W[e*2+1]*h2[1];
      nv[(size_t)idx*EE+e]=tanhf(emb[(((size_t)b*TT+0)*NN+n)*EE+e]*xe);
    }
  }
}

// ---------------- fused d-sum + xg2 gemm (G on the fly) ----------------
// grid (nc=12, js=8, b=8); writes parts[js][b][n][i<=64] and d[b][j] for its j-range
__global__ __launch_bounds__(256) void k_xg2d(
    const float* __restrict__ nv, const float* __restrict__ xs,
    float* __restrict__ parts, float* __restrict__ d)
{
  __shared__ float nvs[NN*EE];        // 28.6 KB: all nv for this b
  __shared__ float dls[96];
  __shared__ float xss[JCH][XSP];
  __shared__ float gs[JCH][XSP];
  __shared__ float red[256];
  int nc = blockIdx.x, js = blockIdx.y, b = blockIdx.z;
  int tid = threadIdx.x;
  int n0 = nc*64;
  int j0 = js*JR, jend = min(NN, j0+JR);
  // stage full nv[b]
  for (int i=tid; i<NN*EE; i+=256) nvs[i] = nv[(size_t)b*NN*EE + i];
  __syncthreads();
  // in-block d for this j-range: d[j] = rsqrt(sum_n relu(nv_j . nv_n))
  {
    int jg = tid>>5, lane = tid&31;
    for (int jr=0; jr<12; jr++){
      int j = j0 + jr*8 + jg;
      float sum = 0.f;
      if (j < jend){
        float a[EE];
        #pragma unroll
        for (int e=0;e<EE;e++) a[e] = nvs[j*EE+e];
        for (int n=lane; n<NN; n+=32){
          float s = 0.f;
          #pragma unroll
          for (int e=0;e<EE;e++) s += a[e]*nvs[n*EE+e];
          sum += fmaxf(s, 0.f);
        }
      }
      sum += __shfl_xor(sum,16,64); sum += __shfl_xor(sum,8,64);
      sum += __shfl_xor(sum,4,64);  sum += __shfl_xor(sum,2,64);
      sum += __shfl_xor(sum,1,64);
      if (lane==0 && j<jend){
        float dv = rsqrtf(sum);
        dls[j-j0] = dv;
        d[b*NN+j] = dv;      // redundant across nc, same value
      }
    }
  }
  __syncthreads();
  int ig = tid & 15, ng = tid >> 4;       // acc: i=ig*4.., n=ng*4..
  int jg2 = tid >> 4, ng2 = tid & 15;     // G-compute: rows jg2*2+{0,1}
  int n2 = tid & 63, q = tid >> 6;        // col64
  float acc[4][4];
  #pragma unroll
  for (int r=0;r<4;r++){ acc[r][0]=0;acc[r][1]=0;acc[r][2]=0;acc[r][3]=0; }
  float a64p = 0.f;
  for (int jc=j0; jc<jend; jc+=JCH){
    int cnt = min(JCH, jend-jc);
    __syncthreads();
    // stage d_j-scaled xs rows
    for (int idx=tid; idx<JCH*64; idx+=256){
      int r = idx>>6, ii = idx&63;
      xss[r][ii] = (r<cnt) ? dls[jc-j0+r]*xs[((size_t)b*NN+jc+r)*XSP+ii] : 0.f;
    }
    if (tid < JCH)
      xss[tid][64] = (tid<cnt) ? dls[jc-j0+tid]*xs[((size_t)b*NN+jc+tid)*XSP+64] : 0.f;
    // compute G tile (2 rows x 4 cols per thread) from nvs
    {
      int r0 = jg2*2;
      int nb = n0 + ng2*4;
      float g[2][4];
      #pragma unroll
      for (int r=0;r<2;r++){ g[r][0]=0;g[r][1]=0;g[r][2]=0;g[r][3]=0; }
      #pragma unroll
      for (int e=0;e<EE;e++){
        float b0 = (r0  <cnt)? nvs[(jc+r0  )*EE+e] : 0.f;
        float b1 = (r0+1<cnt)? nvs[(jc+r0+1)*EE+e] : 0.f;
        float a0 = (nb  <NN)? nvs[(nb  )*EE+e] : 0.f;
        float a1 = (nb+1<NN)? nvs[(nb+1)*EE+e] : 0.f;
        float a2 = (nb+2<NN)? nvs[(nb+2)*EE+e] : 0.f;
        float a3 = (nb+3<NN)? nvs[(nb+3)*EE+e] : 0.f;
        g[0][0]+=b0*a0; g[0][1]+=b0*a1; g[0][2]+=b0*a2; g[0][3]+=b0*a3;
        g[1][0]+=b1*a0; g[1][1]+=b1*a1; g[1][2]+=b1*a2; g[1][3]+=b1*a3;
      }
      #pragma unroll
      for (int r=0;r<2;r++){
        float4 v = { fmaxf(g[r][0],0.f), fmaxf(g[r][1],0.f),
                     fmaxf(g[r][2],0.f), fmaxf(g[r][3],0.f) };
        *(float4*)&gs[r0+r][ng2*4] = v;
      }
    }
    __syncthreads();
    // main accumulation
    for (int jj=0; jj<cnt; ++jj){
      float4 g4 = *(const float4*)&gs[jj][ng*4];
      float4 x4 = *(const float4*)&xss[jj][ig*4];
      acc[0][0]+=g4.x*x4.x; acc[0][1]+=g4.x*x4.y; acc[0][2]+=g4.x*x4.z; acc[0][3]+=g4.x*x4.w;
      acc[1][0]+=g4.y*x4.x; acc[1][1]+=g4.y*x4.y; acc[1][2]+=g4.y*x4.z; acc[1][3]+=g4.y*x4.w;
      acc[2][0]+=g4.z*x4.x; acc[2][1]+=g4.z*x4.y; acc[2][2]+=g4.z*x4.z; acc[2][3]+=g4.z*x4.w;
      acc[3][0]+=g4.w*x4.x; acc[3][1]+=g4.w*x4.y; acc[3][2]+=g4.w*x4.z; acc[3][3]+=g4.w*x4.w;
    }
    // col64 partials (rows >= cnt zeroed)
    #pragma unroll
    for (int r=0;r<8;r++){
      int jj = q*8 + r;
      a64p += gs[jj][n2]*xss[jj][64];
    }
  }
  // write main acc (pad rows NN..NP-1 absorb out-of-range n)
  #pragma unroll
  for (int r=0;r<4;r++){
    int n = n0 + ng*4 + r;
    float4 v = { acc[r][0], acc[r][1], acc[r][2], acc[r][3] };
    *(float4*)&parts[(((size_t)js*BB+b)*NP+n)*XSP + ig*4] = v;
  }
  __syncthreads();
  red[q*64 + n2] = a64p;
  __syncthreads();
  if (tid < 64){
    float s = red[tid] + red[64+tid] + red[128+tid] + red[192+tid];
    parts[(((size_t)js*BB+b)*NP + n0+tid)*XSP + 64] = s;
  }
}

// ---------------- gate transform ----------------
__global__ __launch_bounds__(256) void k_tr_gate(
    const float* __restrict__ wg, const float* __restrict__ bg,
    const float* __restrict__ parts, const float* __restrict__ d,
    const float* __restrict__ xsg,
    const float* __restrict__ cur_ct, const float* __restrict__ h,
    const float* __restrict__ emb, int t,
    const float* __restrict__ f1W, const float* __restrict__ f1b,
    const float* __restrict__ f2W, const float* __restrict__ f2b,
    const float* __restrict__ f3W, const float* __restrict__ f3b,
    float* __restrict__ rbuf, float* __restrict__ xsu, float* __restrict__ nv)
{
  __shared__ float xg2s[BB][66];
  __shared__ float xss[BB][DIN];
  __shared__ float cs[BB][DIN];
  __shared__ float h1s[BB][16];
  __shared__ float h2s[BB][2];
  int n = blockIdx.x;
  int tid = threadIdx.x;
  for (int idx=tid; idx<BB*65; idx+=256){
    int b = idx/65, i = idx - b*65;
    float s = 0.f;
    #pragma unroll
    for (int js2=0; js2<JS; js2++)
      s += parts[(((size_t)js2*BB+b)*NP+n)*XSP + i];
    xg2s[b][i] = d[b*NN+n]*s;
  }
  for (int idx=tid; idx<BB*DIN; idx+=256){
    int b = idx/DIN, i = idx - b*DIN;
    xss[b][i] = xsg[((size_t)b*NN+n)*XSP + i];
  }
  __syncthreads();
  {
    int o = tid & 127, half = tid >> 7;
    const float* w0p = wg + ((size_t)n*2+0)*DIN*OG + o;
    const float* w1p = wg + ((size_t)n*2+1)*DIN*OG + o;
    float bgv = bg[n*OG+o];
    float acc[4]; acc[0]=bgv; acc[1]=bgv; acc[2]=bgv; acc[3]=bgv;
    for (int i=0;i<65;i++){
      float w0 = w0p[i*OG], w1 = w1p[i*OG];
      #pragma unroll
      for (int bb=0;bb<4;bb++){
        int b = 2*bb+half;
        acc[bb] += xss[b][i]*w0 + xg2s[b][i]*w1;
      }
    }
    #pragma unroll
    for (int bb=0;bb<4;bb++){
      int b = 2*bb+half;
      float v = sigmf(acc[bb]);
      if (o < 64){
        float cv = v * h[((size_t)b*NN+n)*HH + o];
        xsu[((size_t)b*NN+n)*XSP + 1 + o] = cv;
        cs[b][1+o] = cv;
      } else {
        rbuf[((size_t)b*NN+n)*HH + (o-64)] = v;
      }
    }
    if (o == 64){
      #pragma unroll
      for (int bb=0;bb<4;bb++){
        int b = 2*bb+half;
        float x = cur_ct[(size_t)b*NN+n];
        cs[b][0] = x;
        xsu[((size_t)b*NN+n)*XSP] = x;
      }
    }
  }
  __syncthreads();
  if (tid < BB*16){
    int b=tid>>4, k=tid&15;
    const float* wr = f1W + k*DIN;
    float s = f1b[k];
    #pragma unroll
    for (int i=0;i<DIN;i++) s += cs[b][i]*wr[i];
    h1s[b][k] = sigmf(s);
  }
  __syncthreads();
  if (tid < BB*2){
    int b=tid>>1, k=tid&1;
    float s = f2b[k];
    #pragma unroll
    for (int q2=0;q2<16;q2++) s += h1s[b][q2]*f2W[k*16+q2];
    h2s[b][k] = sigmf(s);
  }
  __syncthreads();
  if (tid < BB*EE){
    int b=tid/EE, e=tid-b*EE;
    float xe = f3b[e] + f3W[e*2]*h2s[b][0] + f3W[e*2+1]*h2s[b][1];
    nv[((size_t)b*NN+n)*EE+e] = tanhf(emb[(((size_t)b*TT+t)*NN+n)*EE+e]*xe);
  }
}

// ---------------- update transform ----------------
__global__ __launch_bounds__(256) void k_tr_upd(
    const float* __restrict__ wu, const float* __restrict__ bu,
    const float* __restrict__ parts, const float* __restrict__ d,
    const float* __restrict__ xsu,
    const float* __restrict__ rbuf, float* __restrict__ h,
    float* __restrict__ cur, int c, int t,
    const float* __restrict__ emb,
    const float* __restrict__ f1W, const float* __restrict__ f1b,
    const float* __restrict__ f2W, const float* __restrict__ f2b,
    const float* __restrict__ f3W, const float* __restrict__ f3b,
    float* __restrict__ xsg, float* __restrict__ nv,
    const float* __restrict__ predW, const float* __restrict__ predB,
    const float* __restrict__ skipW, const float* __restrict__ skipB,
    float* __restrict__ out)
{
  __shared__ float xg2s[BB][66];
  __shared__ float xss[BB][DIN];
  __shared__ float hs[BB][HH];
  __shared__ float h1s[BB][16];
  __shared__ float h2s[BB][2];
  __shared__ float xns[BB];
  int n = blockIdx.x;
  int tid = threadIdx.x;
  for (int idx=tid; idx<BB*65; idx+=256){
    int b = idx/65, i = idx - b*65;
    float s = 0.f;
    #pragma unroll
    for (int js2=0; js2<JS; js2++)
      s += parts[(((size_t)js2*BB+b)*NP+n)*XSP + i];
    xg2s[b][i] = d[b*NN+n]*s;
  }
  for (int idx=tid; idx<BB*DIN; idx+=256){
    int b = idx/DIN, i = idx - b*DIN;
    xss[b][i] = xsu[((size_t)b*NN+n)*XSP + i];
  }
  __syncthreads();
  {
    int o = tid & 63, grp = tid >> 6;
    const float* w0p = wu + ((size_t)n*2+0)*DIN*OU + o;
    const float* w1p = wu + ((size_t)n*2+1)*DIN*OU + o;
    float acc[2];
    acc[0] = bu[n*OU+o]; acc[1] = acc[0];
    for (int i=0;i<65;i++){
      float w0 = w0p[i*OU], w1 = w1p[i*OU];
      #pragma unroll
      for (int bb=0;bb<2;bb++){
        int b = grp + 4*bb;
        acc[bb] += xss[b][i]*w0 + xg2s[b][i]*w1;
      }
    }
    #pragma unroll
    for (int bb=0;bb<2;bb++){
      int b = grp + 4*bb;
      float hc = tanhf(acc[bb]);
      float r = rbuf[((size_t)b*NN+n)*HH+o];
      float hold = h[((size_t)b*NN+n)*HH+o];
      float hn = r*hold + (1.f-r)*hc;
      h[((size_t)b*NN+n)*HH+o] = hn;
      hs[b][o] = hn;
    }
  }
  __syncthreads();
  if (t < TT-1){
    if (tid < BB){
      float x = cur[(((size_t)c*TT + (t+1))*BB + tid)*NN + n];
      xns[tid] = x;
      xsg[((size_t)tid*NN+n)*XSP] = x;
    }
    for (int idx=tid; idx<BB*HH; idx+=256){
      int b = idx>>6, oo = idx&63;
      xsg[((size_t)b*NN+n)*XSP + 1 + oo] = hs[b][oo];
    }
    __syncthreads();
    if (tid < BB*16){
      int b=tid>>4, k=tid&15;
      const float* wr = f1W + k*DIN;
      float s = f1b[k] + wr[0]*xns[b];
      #pragma unroll
      for (int oo=0;oo<HH;oo++) s += hs[b][oo]*wr[1+oo];
      h1s[b][k] = sigmf(s);
    }
    __syncthreads();
    if (tid < BB*2){
      int b=tid>>1, k=tid&1;
      float s = f2b[k];
      #pragma unroll
      for (int q2=0;q2<16;q2++) s += h1s[b][q2]*f2W[k*16+q2];
      h2s[b][k] = sigmf(s);
    }
    __syncthreads();
    if (tid < BB*EE){
      int b=tid/EE, e=tid-b*EE;
      float xe = f3b[e] + f3W[e*2]*h2s[b][0] + f3W[e*2+1]*h2s[b][1];
      nv[((size_t)b*NN+n)*EE+e] =
        tanhf(emb[(((size_t)b*TT+(t+1))*NN+n)*EE+e]*xe);
    }
  } else {
    if (tid < BB*TT){
      int b = tid/TT, ot = tid - b*TT;
      const float* pw = predW + ((size_t)c*TT + ot)*HH;
      float pv = predB[c*TT+ot];
      #pragma unroll
      for (int q2=0;q2<HH;q2++) pv += hs[b][q2]*pw[q2];
      size_t oi = ((size_t)b*TT+ot)*NN + n;
      if (c == 0){
        out[oi] = pv;
        const float* sw = skipW + (size_t)ot*HH;
        float sk = skipB[ot];
        #pragma unroll
        for (int q2=0;q2<HH;q2++) sk += hs[b][q2]*sw[q2];
        cur[(((size_t)TT+ot)*BB + b)*NN + n] =
            cur[((size_t)ot*BB + b)*NN + n] - sk;
      } else {
        out[oi] += pv;
      }
    }
  }
}

extern "C" void kernel_launch(void* const* d_in, const int* in_sizes, int n_in,
                              void* d_out, int out_size, void* d_ws, size_t ws_size,
                              hipStream_t stream){
  const float* src  = (const float*)d_in[0];
  const float* ne   = (const float*)d_in[1];
  const float* te   = (const float*)d_in[2];
  const float* de   = (const float*)d_in[3];
  const float* wp_g = (const float*)d_in[4];
  const float* bp_g = (const float*)d_in[5];
  const float* f1W_g= (const float*)d_in[6];
  const float* f1b_g= (const float*)d_in[7];
  const float* f2W_g= (const float*)d_in[8];
  const float* f2b_g= (const float*)d_in[9];
  const float* f3W_g= (const float*)d_in[10];
  const float* f3b_g= (const float*)d_in[11];
  const float* wp_u = (const float*)d_in[12];
  const float* bp_u = (const float*)d_in[13];
  const float* f1W_u= (const float*)d_in[14];
  const float* f1b_u= (const float*)d_in[15];
  const float* f2W_u= (const float*)d_in[16];
  const float* f2b_u= (const float*)d_in[17];
  const float* f3W_u= (const float*)d_in[18];
  const float* f3b_u= (const float*)d_in[19];
  const float* predW= (const float*)d_in[20];
  const float* predB= (const float*)d_in[21];
  const float* skipW= (const float*)d_in[22];
  const float* skipB= (const float*)d_in[23];

  float* ws   = (float*)d_ws;
  float* emb  = ws;
  float* cur  = emb  + (size_t)BB*TT*NN*EE;
  float* wg   = cur  + (size_t)2*TT*BB*NN;
  float* bg   = wg   + (size_t)NN*2*DIN*OG;
  float* wu   = bg   + (size_t)NN*OG;
  float* bu   = wu   + (size_t)NN*2*DIN*OU;
  float* h    = bu   + (size_t)NN*OU;
  float* xsg  = h    + (size_t)BB*NN*HH;
  float* xsu  = xsg  + (size_t)BB*NN*XSP;
  float* nv   = xsu  + (size_t)BB*NN*XSP;
  float* dbuf = nv   + (size_t)BB*NN*EE;
  float* parts= dbuf + (size_t)BB*NN;
  float* rbuf = parts+ (size_t)JS*BB*NP*XSP;
  float* outp = (float*)d_out;

  k_emb<<<(BB*TT*NN+255)/256, 256, 0, stream>>>(src, ne, te, de, emb, cur);

  for (int c=0;c<2;c++){
    k_prep_w2<OG><<<dim3(2*DIN,2),256,0,stream>>>(ne, wp_g + (size_t)c*EE*2*DIN*OG, wg);
    k_prep_w2<OU><<<dim3(2*DIN,2),256,0,stream>>>(ne, wp_u + (size_t)c*EE*2*DIN*OU, wu);
    k_misc<<<1024,256,0,stream>>>(ne, bp_g + (size_t)c*EE*OG, bp_u + (size_t)c*EE*OU,
        bg, bu, h, cur + (size_t)c*TT*BB*NN,
        f1W_g + c*16*DIN, f1b_g + c*16, f2W_g + c*32, f2b_g + c*2,
        f3W_g + c*EE*2, f3b_g + c*EE, emb, xsg, nv);
    for (int t=0;t<TT;t++){
      k_xg2d<<<dim3(12,JS,BB),256,0,stream>>>(nv, xsg, parts, dbuf);
      k_tr_gate<<<NN,256,0,stream>>>(wg, bg, parts, dbuf, xsg,
          cur + ((size_t)c*TT+t)*BB*NN, h, emb, t,
          f1W_u + c*16*DIN, f1b_u + c*16, f2W_u + c*32, f2b_u + c*2,
          f3W_u + c*EE*2, f3b_u + c*EE, rbuf, xsu, nv);
      k_xg2d<<<dim3(12,JS,BB),256,0,stream>>>(nv, xsu, parts, dbuf);
      k_tr_upd<<<NN,256,0,stream>>>(wu, bu, parts, dbuf, xsu, rbuf, h,
          cur, c, t, emb,
          f1W_g + c*16*DIN, f1b_g + c*16, f2W_g + c*32, f2b_g + c*2,
          f3W_g + c*EE*2, f3b_g + c*EE,
          xsg, nv, predW, predB, skipW, skipB, outp);
    }
  }
}

// Round 5
// 3676.996 us; speedup vs baseline: 3.3891x; 1.0376x over previous
//
#include <hip/hip_runtime.h>
#include <math.h>

#define BB 8
#define TT 12
#define NN 716
#define EE 10
#define HH 64
#define DIN 65
#define OG 128
#define OU 64
#define XSP 68     // padded xs / parts row stride
#define JS 12      // j-split for xg2 gemm
#define JRX 60     // j per split (12*60=720 >= 716)
#define NTN 128    // n-tile in xg2
#define NP 768     // padded n for parts

__device__ __forceinline__ float sigmf(float x){ return 1.0f/(1.0f+__expf(-x)); }

// ---------------- emb precompute + cur0 ----------------
__global__ void k_emb(const float* __restrict__ src, const float* __restrict__ ne,
                      const float* __restrict__ te, const float* __restrict__ de,
                      float* __restrict__ emb, float* __restrict__ cur){
  int idx = blockIdx.x*256 + threadIdx.x;
  if (idx >= BB*TT*NN) return;
  int n = idx % NN; int t = (idx/NN) % TT; int b = idx/(NN*TT);
  const float* s = src + (size_t)idx*3;
  float x = s[0];
  int ti = (int)(s[1]*288.0f);
  int di = (int)(s[2]);
  size_t eo = ((size_t)b*TT + t)*NN*EE + (size_t)n*EE;
  #pragma unroll
  for (int e=0;e<EE;e++)
    emb[eo+e] = ne[n*EE+e]*te[ti*EE+e]*de[di*EE+e];
  cur[((size_t)t*BB + b)*NN + n] = x;   // cur[0][t][b][n]
}

// ---------------- per-layer w = static@wp ----------------
template<int O>
__global__ __launch_bounds__(256) void k_prep_w2(
    const float* __restrict__ ne, const float* __restrict__ wp,
    float* __restrict__ w)
{
  __shared__ float wps[EE][O];
  int ki = blockIdx.x;           // 0..129
  int half = blockIdx.y;         // 0..1
  int k = ki / DIN, i = ki - k*DIN;
  int tid = threadIdx.x;
  for (int idx=tid; idx<EE*O; idx+=256){
    int e = idx / O, o = idx - e*O;
    wps[e][o] = wp[(((size_t)e*2+k)*DIN+i)*O + o];
  }
  __syncthreads();
  constexpr int NG = 256/O;
  int o = tid & (O-1), ng = tid / O;
  int nend = min(NN, half*358+358);
  for (int n = half*358 + ng; n < nend; n += NG){
    float acc = 0.f;
    #pragma unroll
    for (int e=0;e<EE;e++) acc += ne[n*EE+e]*wps[e][o];
    w[(((size_t)n*2+k)*DIN+i)*O + o] = acc;
  }
}

// ---------------- per-layer misc: biases + h=0 + xs/nv init ----------------
__global__ void k_misc(const float* __restrict__ ne,
                       const float* __restrict__ bp_g, const float* __restrict__ bp_u,
                       float* __restrict__ bg, float* __restrict__ bu,
                       float* __restrict__ h, const float* __restrict__ cur_c,
                       const float* __restrict__ f1W, const float* __restrict__ f1b,
                       const float* __restrict__ f2W, const float* __restrict__ f2b,
                       const float* __restrict__ f3W, const float* __restrict__ f3b,
                       const float* __restrict__ emb,
                       float* __restrict__ xsg, float* __restrict__ nv){
  int mt = blockIdx.x*256 + threadIdx.x;
  int MT = gridDim.x*256;
  for (int i=mt; i<BB*NN*HH; i+=MT) h[i] = 0.f;
  for (int i=mt; i<NN*OG; i+=MT){
    int o=i&(OG-1), n=i>>7; float a=0.f;
    #pragma unroll
    for (int e=0;e<EE;e++) a += ne[n*EE+e]*bp_g[e*OG+o];
    bg[i]=a;
  }
  for (int i=mt; i<NN*OU; i+=MT){
    int o=i&(OU-1), n=i>>6; float a=0.f;
    #pragma unroll
    for (int e=0;e<EE;e++) a += ne[n*EE+e]*bp_u[e*OU+o];
    bu[i]=a;
  }
  for (int idx=mt; idx<BB*NN; idx+=MT){
    int b=idx/NN, n=idx-b*NN;
    float x = cur_c[(size_t)b*NN + n];   // t = 0
    float* xr = xsg + (size_t)idx*XSP;
    xr[0]=x;
    #pragma unroll
    for (int i2=1;i2<XSP;i2++) xr[i2]=0.f;
    float h1[16];
    #pragma unroll
    for (int k=0;k<16;k++) h1[k]=sigmf(f1b[k]+f1W[k*DIN]*x);
    float h2[2];
    #pragma unroll
    for (int k=0;k<2;k++){
      float s=f2b[k];
      #pragma unroll
      for (int q=0;q<16;q++) s+=f2W[k*16+q]*h1[q];
      h2[k]=sigmf(s);
    }
    #pragma unroll
    for (int e=0;e<EE;e++){
      float xe=f3b[e]+f3W[e*2]*h2[0]+f3W[e*2+1]*h2[1];
      nv[(size_t)idx*EE+e]=tanhf(emb[(((size_t)b*TT+0)*NN+n)*EE+e]*xe);
    }
  }
}

// ---------------- d[b][j] = rsqrt(sum_n relu(nv_j . nv_n)) ----------------
__global__ __launch_bounds__(256) void k_dsum(const float* __restrict__ nv,
                                              float* __restrict__ d){
  __shared__ float c_nv[64][11];
  int jt = blockIdx.x, b = blockIdx.y;
  int tid = threadIdx.x;
  int jg = tid >> 4, ns = tid & 15;
  int jbase = jt*64 + jg*4;
  float a[4][EE];
  #pragma unroll
  for (int r=0;r<4;r++){
    int j = jbase + r;
    #pragma unroll
    for (int e=0;e<EE;e++)
      a[r][e] = (j<NN) ? nv[((size_t)b*NN+j)*EE+e] : 0.f;
  }
  float sums[4] = {0.f,0.f,0.f,0.f};
  for (int ncc=0; ncc<NN; ncc+=64){
    int cnt = min(64, NN-ncc);
    __syncthreads();
    for (int idx=tid; idx<64*EE; idx+=256){
      int r = idx/EE, e = idx - r*EE;
      c_nv[r][e] = (r<cnt) ? nv[((size_t)b*NN+ncc+r)*EE+e] : 0.f;
    }
    __syncthreads();
    float g[4][4];
    #pragma unroll
    for (int r=0;r<4;r++){ g[r][0]=0;g[r][1]=0;g[r][2]=0;g[r][3]=0; }
    #pragma unroll
    for (int e=0;e<EE;e++){
      float c0=c_nv[ns*4+0][e], c1=c_nv[ns*4+1][e], c2=c_nv[ns*4+2][e], c3=c_nv[ns*4+3][e];
      #pragma unroll
      for (int r=0;r<4;r++){
        float av=a[r][e];
        g[r][0]+=av*c0; g[r][1]+=av*c1; g[r][2]+=av*c2; g[r][3]+=av*c3;
      }
    }
    #pragma unroll
    for (int r=0;r<4;r++)
      sums[r] += fmaxf(g[r][0],0.f)+fmaxf(g[r][1],0.f)+fmaxf(g[r][2],0.f)+fmaxf(g[r][3],0.f);
  }
  #pragma unroll
  for (int r=0;r<4;r++){
    float s = sums[r];
    s += __shfl_xor(s,1,64); s += __shfl_xor(s,2,64);
    s += __shfl_xor(s,4,64); s += __shfl_xor(s,8,64);
    sums[r] = s;
  }
  if (ns==0){
    #pragma unroll
    for (int r=0;r<4;r++){
      int j = jbase + r;
      if (j < NN) d[b*NN+j] = rsqrtf(sums[r]);
    }
  }
}

// ---------------- xg2 gemm, G on the fly, 128n x 64i tile, single j-chunk ----------------
// grid (nc=6, js=12, b=8); parts[js][b][n][i<=64]
__global__ __launch_bounds__(256) void k_xg2(
    const float* __restrict__ nv, const float* __restrict__ d,
    const float* __restrict__ xs, float* __restrict__ parts)
{
  __shared__ float a_nv[NTN*11];      // 5632 B   n-tile nv (stride 11)
  __shared__ float b_nv[64*11];       // 2816 B   j-chunk nv (stride 11)
  __shared__ float xss[64][XSP];      // 17408 B  d_j-scaled xs
  __shared__ float gs[64][NTN+4];     // 33792 B  G tile
  int nc = blockIdx.x, js = blockIdx.y, b = blockIdx.z;
  int tid = threadIdx.x;
  int n0 = nc*NTN;
  int j0 = js*JRX;
  int jend = min(NN, j0+JRX);
  int cnt = jend - j0;                // 60 or 56
  // stage a_nv (zero-pad n >= NN)
  for (int idx=tid; idx<NTN*EE; idx+=256){
    int r = idx/EE, e = idx - r*EE;
    int n = n0 + r;
    a_nv[r*11+e] = (n<NN) ? nv[((size_t)b*NN+n)*EE+e] : 0.f;
  }
  // stage b_nv (zero-pad rows >= cnt)
  for (int idx=tid; idx<64*EE; idx+=256){
    int r = idx/EE, e = idx - r*EE;
    b_nv[r*11+e] = (r<cnt) ? nv[((size_t)b*NN+j0+r)*EE+e] : 0.f;
  }
  // stage d_j-scaled xs
  for (int idx=tid; idx<64*64; idx+=256){
    int r = idx>>6, ii = idx&63;
    xss[r][ii] = (r<cnt) ? d[b*NN+j0+r]*xs[((size_t)b*NN+j0+r)*XSP+ii] : 0.f;
  }
  if (tid < 64)
    xss[tid][64] = (tid<cnt) ? d[b*NN+j0+tid]*xs[((size_t)b*NN+j0+tid)*XSP+64] : 0.f;
  __syncthreads();
  // G tile: thread (jg=tid>>4: 4 j's) x (ng3=tid&15: 8 n's)
  {
    int jg = tid>>4, ng3 = tid&15;
    float g[4][8];
    #pragma unroll
    for (int r=0;r<4;r++)
      #pragma unroll
      for (int s2=0;s2<8;s2++) g[r][s2]=0.f;
    #pragma unroll
    for (int e=0;e<EE;e++){
      float bv[4], av[8];
      #pragma unroll
      for (int r=0;r<4;r++) bv[r] = b_nv[(jg*4+r)*11+e];
      #pragma unroll
      for (int s2=0;s2<8;s2++) av[s2] = a_nv[(ng3*8+s2)*11+e];
      #pragma unroll
      for (int r=0;r<4;r++)
        #pragma unroll
        for (int s2=0;s2<8;s2++) g[r][s2] += bv[r]*av[s2];
    }
    #pragma unroll
    for (int r=0;r<4;r++){
      float4 v0 = { fmaxf(g[r][0],0.f), fmaxf(g[r][1],0.f),
                    fmaxf(g[r][2],0.f), fmaxf(g[r][3],0.f) };
      float4 v1 = { fmaxf(g[r][4],0.f), fmaxf(g[r][5],0.f),
                    fmaxf(g[r][6],0.f), fmaxf(g[r][7],0.f) };
      *(float4*)&gs[jg*4+r][ng3*8]   = v0;
      *(float4*)&gs[jg*4+r][ng3*8+4] = v1;
    }
  }
  __syncthreads();
  // main: thread (ng=tid>>3: 4 n's at ng*4) x (ig=tid&7: 8 i's at ig*8)
  int ng = tid >> 3, ig = tid & 7;
  float acc[4][8];
  #pragma unroll
  for (int r=0;r<4;r++)
    #pragma unroll
    for (int s2=0;s2<8;s2++) acc[r][s2]=0.f;
  for (int jj=0; jj<cnt; ++jj){
    float4 g4  = *(const float4*)&gs[jj][ng*4];
    float4 x4a = *(const float4*)&xss[jj][ig*8];
    float4 x4b = *(const float4*)&xss[jj][ig*8+4];
    float gr[4] = {g4.x, g4.y, g4.z, g4.w};
    float xr[8] = {x4a.x,x4a.y,x4a.z,x4a.w, x4b.x,x4b.y,x4b.z,x4b.w};
    #pragma unroll
    for (int r=0;r<4;r++)
      #pragma unroll
      for (int s2=0;s2<8;s2++) acc[r][s2] += gr[r]*xr[s2];
  }
  // write parts
  #pragma unroll
  for (int r=0;r<4;r++){
    int n = n0 + ng*4 + r;    // < NP always
    float4 v0 = { acc[r][0], acc[r][1], acc[r][2], acc[r][3] };
    float4 v1 = { acc[r][4], acc[r][5], acc[r][6], acc[r][7] };
    size_t base = (((size_t)js*BB+b)*NP+n)*XSP;
    *(float4*)&parts[base + ig*8]     = v0;
    *(float4*)&parts[base + ig*8 + 4] = v1;
  }
  // col 64
  if (tid < NTN){
    float s = 0.f;
    for (int jj=0; jj<cnt; ++jj) s += gs[jj][tid]*xss[jj][64];
    parts[(((size_t)js*BB+b)*NP + n0+tid)*XSP + 64] = s;
  }
}

// ---------------- gate transform ----------------
__global__ __launch_bounds__(256) void k_tr_gate(
    const float* __restrict__ wg, const float* __restrict__ bg,
    const float* __restrict__ parts, const float* __restrict__ d,
    const float* __restrict__ xsg,
    const float* __restrict__ cur_ct, const float* __restrict__ h,
    const float* __restrict__ emb, int t,
    const float* __restrict__ f1W, const float* __restrict__ f1b,
    const float* __restrict__ f2W, const float* __restrict__ f2b,
    const float* __restrict__ f3W, const float* __restrict__ f3b,
    float* __restrict__ rbuf, float* __restrict__ xsu, float* __restrict__ nv)
{
  __shared__ float xg2s[BB][66];
  __shared__ float xss[BB][DIN];
  __shared__ float cs[BB][DIN];
  __shared__ float h1s[BB][16];
  __shared__ float h2s[BB][2];
  int n = blockIdx.x;
  int tid = threadIdx.x;
  for (int idx=tid; idx<BB*65; idx+=256){
    int b = idx/65, i = idx - b*65;
    float s = 0.f;
    #pragma unroll
    for (int js2=0; js2<JS; js2++)
      s += parts[(((size_t)js2*BB+b)*NP+n)*XSP + i];
    xg2s[b][i] = d[b*NN+n]*s;
  }
  for (int idx=tid; idx<BB*DIN; idx+=256){
    int b = idx/DIN, i = idx - b*DIN;
    xss[b][i] = xsg[((size_t)b*NN+n)*XSP + i];
  }
  __syncthreads();
  {
    int o = tid & 127, half = tid >> 7;
    const float* w0p = wg + ((size_t)n*2+0)*DIN*OG + o;
    const float* w1p = wg + ((size_t)n*2+1)*DIN*OG + o;
    float bgv = bg[n*OG+o];
    float acc[4]; acc[0]=bgv; acc[1]=bgv; acc[2]=bgv; acc[3]=bgv;
    for (int i=0;i<65;i++){
      float w0 = w0p[i*OG], w1 = w1p[i*OG];
      #pragma unroll
      for (int bb=0;bb<4;bb++){
        int b = 2*bb+half;
        acc[bb] += xss[b][i]*w0 + xg2s[b][i]*w1;
      }
    }
    #pragma unroll
    for (int bb=0;bb<4;bb++){
      int b = 2*bb+half;
      float v = sigmf(acc[bb]);
      if (o < 64){
        float cv = v * h[((size_t)b*NN+n)*HH + o];
        xsu[((size_t)b*NN+n)*XSP + 1 + o] = cv;
        cs[b][1+o] = cv;
      } else {
        rbuf[((size_t)b*NN+n)*HH + (o-64)] = v;
      }
    }
    if (o == 64){
      #pragma unroll
      for (int bb=0;bb<4;bb++){
        int b = 2*bb+half;
        float x = cur_ct[(size_t)b*NN+n];
        cs[b][0] = x;
        xsu[((size_t)b*NN+n)*XSP] = x;
      }
    }
  }
  __syncthreads();
  if (tid < BB*16){
    int b=tid>>4, k=tid&15;
    const float* wr = f1W + k*DIN;
    float s = f1b[k];
    #pragma unroll
    for (int i=0;i<DIN;i++) s += cs[b][i]*wr[i];
    h1s[b][k] = sigmf(s);
  }
  __syncthreads();
  if (tid < BB*2){
    int b=tid>>1, k=tid&1;
    float s = f2b[k];
    #pragma unroll
    for (int q2=0;q2<16;q2++) s += h1s[b][q2]*f2W[k*16+q2];
    h2s[b][k] = sigmf(s);
  }
  __syncthreads();
  if (tid < BB*EE){
    int b=tid/EE, e=tid-b*EE;
    float xe = f3b[e] + f3W[e*2]*h2s[b][0] + f3W[e*2+1]*h2s[b][1];
    nv[((size_t)b*NN+n)*EE+e] = tanhf(emb[(((size_t)b*TT+t)*NN+n)*EE+e]*xe);
  }
}

// ---------------- update transform ----------------
__global__ __launch_bounds__(256) void k_tr_upd(
    const float* __restrict__ wu, const float* __restrict__ bu,
    const float* __restrict__ parts, const float* __restrict__ d,
    const float* __restrict__ xsu,
    const float* __restrict__ rbuf, float* __restrict__ h,
    float* __restrict__ cur, int c, int t,
    const float* __restrict__ emb,
    const float* __restrict__ f1W, const float* __restrict__ f1b,
    const float* __restrict__ f2W, const float* __restrict__ f2b,
    const float* __restrict__ f3W, const float* __restrict__ f3b,
    float* __restrict__ xsg, float* __restrict__ nv,
    const float* __restrict__ predW, const float* __restrict__ predB,
    const float* __restrict__ skipW, const float* __restrict__ skipB,
    float* __restrict__ out)
{
  __shared__ float xg2s[BB][66];
  __shared__ float xss[BB][DIN];
  __shared__ float hs[BB][HH];
  __shared__ float h1s[BB][16];
  __shared__ float h2s[BB][2];
  __shared__ float xns[BB];
  int n = blockIdx.x;
  int tid = threadIdx.x;
  for (int idx=tid; idx<BB*65; idx+=256){
    int b = idx/65, i = idx - b*65;
    float s = 0.f;
    #pragma unroll
    for (int js2=0; js2<JS; js2++)
      s += parts[(((size_t)js2*BB+b)*NP+n)*XSP + i];
    xg2s[b][i] = d[b*NN+n]*s;
  }
  for (int idx=tid; idx<BB*DIN; idx+=256){
    int b = idx/DIN, i = idx - b*DIN;
    xss[b][i] = xsu[((size_t)b*NN+n)*XSP + i];
  }
  __syncthreads();
  {
    int o = tid & 63, grp = tid >> 6;
    const float* w0p = wu + ((size_t)n*2+0)*DIN*OU + o;
    const float* w1p = wu + ((size_t)n*2+1)*DIN*OU + o;
    float acc[2];
    acc[0] = bu[n*OU+o]; acc[1] = acc[0];
    for (int i=0;i<65;i++){
      float w0 = w0p[i*OU], w1 = w1p[i*OU];
      #pragma unroll
      for (int bb=0;bb<2;bb++){
        int b = grp + 4*bb;
        acc[bb] += xss[b][i]*w0 + xg2s[b][i]*w1;
      }
    }
    #pragma unroll
    for (int bb=0;bb<2;bb++){
      int b = grp + 4*bb;
      float hc = tanhf(acc[bb]);
      float r = rbuf[((size_t)b*NN+n)*HH+o];
      float hold = h[((size_t)b*NN+n)*HH+o];
      float hn = r*hold + (1.f-r)*hc;
      h[((size_t)b*NN+n)*HH+o] = hn;
      hs[b][o] = hn;
    }
  }
  __syncthreads();
  if (t < TT-1){
    if (tid < BB){
      float x = cur[(((size_t)c*TT + (t+1))*BB + tid)*NN + n];
      xns[tid] = x;
      xsg[((size_t)tid*NN+n)*XSP] = x;
    }
    for (int idx=tid; idx<BB*HH; idx+=256){
      int b = idx>>6, oo = idx&63;
      xsg[((size_t)b*NN+n)*XSP + 1 + oo] = hs[b][oo];
    }
    __syncthreads();
    if (tid < BB*16){
      int b=tid>>4, k=tid&15;
      const float* wr = f1W + k*DIN;
      float s = f1b[k] + wr[0]*xns[b];
      #pragma unroll
      for (int oo=0;oo<HH;oo++) s += hs[b][oo]*wr[1+oo];
      h1s[b][k] = sigmf(s);
    }
    __syncthreads();
    if (tid < BB*2){
      int b=tid>>1, k=tid&1;
      float s = f2b[k];
      #pragma unroll
      for (int q2=0;q2<16;q2++) s += h1s[b][q2]*f2W[k*16+q2];
      h2s[b][k] = sigmf(s);
    }
    __syncthreads();
    if (tid < BB*EE){
      int b=tid/EE, e=tid-b*EE;
      float xe = f3b[e] + f3W[e*2]*h2s[b][0] + f3W[e*2+1]*h2s[b][1];
      nv[((size_t)b*NN+n)*EE+e] =
        tanhf(emb[(((size_t)b*TT+(t+1))*NN+n)*EE+e]*xe);
    }
  } else {
    if (tid < BB*TT){
      int b = tid/TT, ot = tid - b*TT;
      const float* pw = predW + ((size_t)c*TT + ot)*HH;
      float pv = predB[c*TT+ot];
      #pragma unroll
      for (int q2=0;q2<HH;q2++) pv += hs[b][q2]*pw[q2];
      size_t oi = ((size_t)b*TT+ot)*NN + n;
      if (c == 0){
        out[oi] = pv;
        const float* sw = skipW + (size_t)ot*HH;
        float sk = skipB[ot];
        #pragma unroll
        for (int q2=0;q2<HH;q2++) sk += hs[b][q2]*sw[q2];
        cur[(((size_t)TT+ot)*BB + b)*NN + n] =
            cur[((size_t)ot*BB + b)*NN + n] - sk;
      } else {
        out[oi] += pv;
      }
    }
  }
}

extern "C" void kernel_launch(void* const* d_in, const int* in_sizes, int n_in,
                              void* d_out, int out_size, void* d_ws, size_t ws_size,
                              hipStream_t stream){
  const float* src  = (const float*)d_in[0];
  const float* ne   = (const float*)d_in[1];
  const float* te   = (const float*)d_in[2];
  const float* de   = (const float*)d_in[3];
  const float* wp_g = (const float*)d_in[4];
  const float* bp_g = (const float*)d_in[5];
  const float* f1W_g= (const float*)d_in[6];
  const float* f1b_g= (const float*)d_in[7];
  const float* f2W_g= (const float*)d_in[8];
  const float* f2b_g= (const float*)d_in[9];
  const float* f3W_g= (const float*)d_in[10];
  const float* f3b_g= (const float*)d_in[11];
  const float* wp_u = (const float*)d_in[12];
  const float* bp_u = (const float*)d_in[13];
  const float* f1W_u= (const float*)d_in[14];
  const float* f1b_u= (const float*)d_in[15];
  const float* f2W_u= (const float*)d_in[16];
  const float* f2b_u= (const float*)d_in[17];
  const float* f3W_u= (const float*)d_in[18];
  const float* f3b_u= (const float*)d_in[19];
  const float* predW= (const float*)d_in[20];
  const float* predB= (const float*)d_in[21];
  const float* skipW= (const float*)d_in[22];
  const float* skipB= (const float*)d_in[23];

  float* ws   = (float*)d_ws;
  float* emb  = ws;
  float* cur  = emb  + (size_t)BB*TT*NN*EE;
  float* wg   = cur  + (size_t)2*TT*BB*NN;
  float* bg   = wg   + (size_t)NN*2*DIN*OG;
  float* wu   = bg   + (size_t)NN*OG;
  float* bu   = wu   + (size_t)NN*2*DIN*OU;
  float* h    = bu   + (size_t)NN*OU;
  float* xsg  = h    + (size_t)BB*NN*HH;
  float* xsu  = xsg  + (size_t)BB*NN*XSP;
  float* nv   = xsu  + (size_t)BB*NN*XSP;
  float* dbuf = nv   + (size_t)BB*NN*EE;
  float* parts= dbuf + (size_t)BB*NN;
  float* rbuf = parts+ (size_t)JS*BB*NP*XSP;
  float* outp = (float*)d_out;

  k_emb<<<(BB*TT*NN+255)/256, 256, 0, stream>>>(src, ne, te, de, emb, cur);

  for (int c=0;c<2;c++){
    k_prep_w2<OG><<<dim3(2*DIN,2),256,0,stream>>>(ne, wp_g + (size_t)c*EE*2*DIN*OG, wg);
    k_prep_w2<OU><<<dim3(2*DIN,2),256,0,stream>>>(ne, wp_u + (size_t)c*EE*2*DIN*OU, wu);
    k_misc<<<1024,256,0,stream>>>(ne, bp_g + (size_t)c*EE*OG, bp_u + (size_t)c*EE*OU,
        bg, bu, h, cur + (size_t)c*TT*BB*NN,
        f1W_g + c*16*DIN, f1b_g + c*16, f2W_g + c*32, f2b_g + c*2,
        f3W_g + c*EE*2, f3b_g + c*EE, emb, xsg, nv);
    for (int t=0;t<TT;t++){
      k_dsum<<<dim3(12,BB),256,0,stream>>>(nv, dbuf);
      k_xg2<<<dim3(6,JS,BB),256,0,stream>>>(nv, dbuf, xsg, parts);
      k_tr_gate<<<NN,256,0,stream>>>(wg, bg, parts, dbuf, xsg,
          cur + ((size_t)c*TT+t)*BB*NN, h, emb, t,
          f1W_u + c*16*DIN, f1b_u + c*16, f2W_u + c*32, f2b_u + c*2,
          f3W_u + c*EE*2, f3b_u + c*EE, rbuf, xsu, nv);
      k_dsum<<<dim3(12,BB),256,0,stream>>>(nv, dbuf);
      k_xg2<<<dim3(6,JS,BB),256,0,stream>>>(nv, dbuf, xsu, parts);
      k_tr_upd<<<NN,256,0,stream>>>(wu, bu, parts, dbuf, xsu, rbuf, h,
          cur, c, t, emb,
          f1W_g + c*16*DIN, f1b_g + c*16, f2W_g + c*32, f2b_g + c*2,
          f3W_g + c*EE*2, f3b_g + c*EE,
          xsg, nv, predW, predB, skipW, skipB, outp);
    }
  }
}